// Round 3
// baseline (270.830 us; speedup 1.0000x reference)
//
#include <hip/hip_runtime.h>
#include <math.h>

// Problem constants (fixed by setup_inputs): B=16, T=4096, D=512, fp32.
#define BB 16
#define TT 4096
#define DD 512
#define D4 128            // DD / 4 (float4 columns)

constexpr int CC = 256;       // chunks along T
constexpr int LL = TT / CC;   // 16 steps per chunk (compile-time -> full unroll)

// Native clang vector type: required by __builtin_nontemporal_store (HIP's
// float4 is a struct and is rejected). Layout-identical to float4.
typedef float floatx4 __attribute__((ext_vector_type(4)));

__device__ __forceinline__ float sigmf(float v) {
    return 1.0f / (1.0f + expf(-v));
}

// ---------------------------------------------------------------------------
// K1: per-(b, chunk) local scan with zero init (chunk 0: exact init s_{-1}=x0),
// writes only the chunk-end value E_c to `ends` ([b][c][d] layout, coalesced).
// All LL float4 loads are hoisted into registers BEFORE the FMA chain so each
// wave keeps 16 KiB of HBM traffic in flight (MLP >> latency-BW product).
// Block: 256 threads = 2 b-rows x 128 float4 columns. Grid: (CC, BB/2) = 2048.
// ---------------------------------------------------------------------------
__global__ __launch_bounds__(256) void es_chunk_ends(
    const float* __restrict__ x, const float* __restrict__ alpha,
    float* __restrict__ ends)
{
    const int c   = blockIdx.x;
    const int tid = threadIdx.x;
    const int b   = (blockIdx.y << 1) + (tid >> 7);
    const int d4  = tid & 127;

    const float4* xp = reinterpret_cast<const float4*>(x)
                     + ((size_t)b * TT + (size_t)c * LL) * D4 + d4;

    float4 v[LL];
    #pragma unroll
    for (int i = 0; i < LL; ++i) v[i] = xp[(size_t)i * D4];

    const float4 al = reinterpret_cast<const float4*>(alpha)[d4];
    const float ax = sigmf(al.x), ay = sigmf(al.y), az = sigmf(al.z), aw = sigmf(al.w);
    const float fx = 1.0f - ax, fy = 1.0f - ay, fz = 1.0f - az, fw = 1.0f - aw;

    float4 s;
    if (c == 0) {
        s = v[0];                        // virtual s_{-1} = x_0 -> chunk-0 end exact
    } else {
        s.x = s.y = s.z = s.w = 0.0f;    // zero-init local scan
    }

    #pragma unroll
    for (int i = 0; i < LL; ++i) {
        s.x = fmaf(ax, v[i].x, fx * s.x);
        s.y = fmaf(ay, v[i].y, fy * s.y);
        s.z = fmaf(az, v[i].z, fz * s.z);
        s.w = fmaf(aw, v[i].w, fw * s.w);
    }

    reinterpret_cast<float4*>(ends)[((size_t)b * CC + c) * D4 + d4] = s;
}

// ---------------------------------------------------------------------------
// K2: carry scan across chunks, in place: S_c = E_c + (1-a)^LL * S_{c-1}.
// One thread per (b, d4) float4 channel = 2048 threads. Rolling 16-deep
// register prefetch window hides the ~900-cycle strided-load latency.
// ---------------------------------------------------------------------------
__global__ __launch_bounds__(256) void es_carry_scan(
    float* __restrict__ ends, const float* __restrict__ alpha)
{
    const int g  = blockIdx.x * 256 + threadIdx.x;   // 0..2047
    const int b  = g >> 7;
    const int d4 = g & 127;

    const float4 al = reinterpret_cast<const float4*>(alpha)[d4];
    const float ax = sigmf(al.x), ay = sigmf(al.y), az = sigmf(al.z), aw = sigmf(al.w);
    float4 fL;
    fL.x = powf(1.0f - ax, (float)LL);
    fL.y = powf(1.0f - ay, (float)LL);
    fL.z = powf(1.0f - az, (float)LL);
    fL.w = powf(1.0f - aw, (float)LL);

    float4* e = reinterpret_cast<float4*>(ends) + (size_t)b * CC * D4 + d4;

    constexpr int P = 16;
    float4 buf[P];
    #pragma unroll
    for (int j = 0; j < P; ++j) buf[j] = e[(size_t)(1 + j) * D4];   // c = 1..P

    float4 S = e[0];   // S_0 = E_0 (already exact)
    int c = 1;
    while (c + P <= CC) {
        #pragma unroll
        for (int j = 0; j < P; ++j) {
            const float4 v = buf[j];
            const int pf = c + P;                 // prefetch P ahead into this slot
            if (pf < CC) buf[j] = e[(size_t)pf * D4];
            S.x = fmaf(fL.x, S.x, v.x);
            S.y = fmaf(fL.y, S.y, v.y);
            S.z = fmaf(fL.z, S.z, v.z);
            S.w = fmaf(fL.w, S.w, v.w);
            e[(size_t)c * D4] = S;
            ++c;
        }
    }
    // Tail: remaining values already live in buf[0..] from the last window.
    for (int j = 0; c < CC; ++c, ++j) {
        const float4 v = buf[j];
        S.x = fmaf(fL.x, S.x, v.x);
        S.y = fmaf(fL.y, S.y, v.y);
        S.z = fmaf(fL.z, S.z, v.z);
        S.w = fmaf(fL.w, S.w, v.w);
        e[(size_t)c * D4] = S;
    }
}

// ---------------------------------------------------------------------------
// K3: re-read x (expected mostly L3-resident after K1), start each chunk from
// the exact inclusive carry S_{c-1}, write out with non-temporal stores so the
// output stream does not evict x from L2/L3.
// ---------------------------------------------------------------------------
__global__ __launch_bounds__(256) void es_final(
    const float* __restrict__ x, const float* __restrict__ alpha,
    const float* __restrict__ carries, float* __restrict__ out)
{
    const int c   = blockIdx.x;
    const int tid = threadIdx.x;
    const int b   = (blockIdx.y << 1) + (tid >> 7);
    const int d4  = tid & 127;

    float4 s;
    if (c != 0) {   // wave-uniform branch (c is per-block)
        s = reinterpret_cast<const float4*>(carries)[((size_t)b * CC + (c - 1)) * D4 + d4];
    }

    const size_t base = ((size_t)b * TT + (size_t)c * LL) * D4 + d4;
    const float4* xp = reinterpret_cast<const float4*>(x) + base;
    floatx4*      op = reinterpret_cast<floatx4*>(out) + base;

    float4 v[LL];
    #pragma unroll
    for (int i = 0; i < LL; ++i) v[i] = xp[(size_t)i * D4];

    const float4 al = reinterpret_cast<const float4*>(alpha)[d4];
    const float ax = sigmf(al.x), ay = sigmf(al.y), az = sigmf(al.z), aw = sigmf(al.w);
    const float fx = 1.0f - ax, fy = 1.0f - ay, fz = 1.0f - az, fw = 1.0f - aw;

    if (c == 0) s = v[0];   // s_{-1} = x_0

    #pragma unroll
    for (int i = 0; i < LL; ++i) {
        s.x = fmaf(ax, v[i].x, fx * s.x);
        s.y = fmaf(ay, v[i].y, fy * s.y);
        s.z = fmaf(az, v[i].z, fz * s.z);
        s.w = fmaf(aw, v[i].w, fw * s.w);
        floatx4 sv = { s.x, s.y, s.z, s.w };
        __builtin_nontemporal_store(sv, op + (size_t)i * D4);
    }
}

// ---------------------------------------------------------------------------
// Fallback: full serial scan per (b, d4) column if ws is too small to chunk.
// ---------------------------------------------------------------------------
__global__ __launch_bounds__(256) void es_serial(
    const float* __restrict__ x, const float* __restrict__ alpha,
    float* __restrict__ out)
{
    const int g  = blockIdx.x * 256 + threadIdx.x;   // 0..2047
    const int b  = g >> 7;
    const int d4 = g & 127;

    const float4 al = reinterpret_cast<const float4*>(alpha)[d4];
    const float ax = sigmf(al.x), ay = sigmf(al.y), az = sigmf(al.z), aw = sigmf(al.w);
    const float fx = 1.0f - ax, fy = 1.0f - ay, fz = 1.0f - az, fw = 1.0f - aw;

    const float4* xp = reinterpret_cast<const float4*>(x) + (size_t)b * TT * D4 + d4;
    float4*       op = reinterpret_cast<float4*>(out) + (size_t)b * TT * D4 + d4;

    float4 s = xp[0];
    #pragma unroll 4
    for (int t = 0; t < TT; ++t) {
        const float4 v = xp[(size_t)t * D4];
        s.x = fmaf(ax, v.x, fx * s.x);
        s.y = fmaf(ay, v.y, fy * s.y);
        s.z = fmaf(az, v.z, fz * s.z);
        s.w = fmaf(aw, v.w, fw * s.w);
        op[(size_t)t * D4] = s;
    }
}

extern "C" void kernel_launch(void* const* d_in, const int* in_sizes, int n_in,
                              void* d_out, int out_size, void* d_ws, size_t ws_size,
                              hipStream_t stream)
{
    const float* x     = (const float*)d_in[0];
    const float* alpha = (const float*)d_in[1];
    float*       out   = (float*)d_out;

    const size_t need = (size_t)BB * CC * DD * sizeof(float);   // 8 MiB carry buffer
    if (ws_size < need) {
        es_serial<<<dim3(8), 256, 0, stream>>>(x, alpha, out);
        return;
    }

    float* ends = (float*)d_ws;
    es_chunk_ends<<<dim3(CC, BB / 2), 256, 0, stream>>>(x, alpha, ends);
    es_carry_scan<<<dim3(8), 256, 0, stream>>>(ends, alpha);
    es_final<<<dim3(CC, BB / 2), 256, 0, stream>>>(x, alpha, ends, out);
}